// Round 1
// baseline (224.683 us; speedup 1.0000x reference)
//
#include <hip/hip_runtime.h>
#include <math.h>

#define NVIEW 8
#define CIN   32
#define HF    128
#define WF    128
#define C1    32   // hidden 1 (== W1 out)
#define C2    16
#define C3    8
#define RESO  64

// ---- shared helpers (same expression in k_msum and k_main so masks agree) ----

static __device__ __forceinline__ float vox_coord(int idx, float b) {
    const float VOXEL = (float)(0.3 / 64.0);
    const float HALFV = (float)(0.3 / 128.0);
    return (float)idx * VOXEL + HALFV + b;
}

static __device__ __forceinline__ void proj_ixiy(const float* M, float x, float y, float z,
                                                 float img_w, float img_h,
                                                 float& ix, float& iy, float& zc) {
    float u  = M[0]*x + M[1]*y + M[2]*z  + M[3];
    float vv = M[4]*x + M[5]*y + M[6]*z  + M[7];
    zc       = M[8]*x + M[9]*y + M[10]*z + M[11];
    float gx = (u  / zc) / img_w - 1.0f;
    float gy = (vv / zc) / img_h - 1.0f;
    ix = (gx + 1.0f) * 0.5f * (float)(WF - 1);
    iy = (gy + 1.0f) * 0.5f * (float)(HF - 1);
}

// ---- K0: w2pixel[v] = Ks[v] (3x3) @ ref_poses[v] (3x4)  -> mats[v*12] ----
__global__ void k_mats(const float* __restrict__ Ks, const float* __restrict__ poses,
                       float* __restrict__ mats) {
    int t = threadIdx.x;
    if (t < NVIEW * 12) {
        int v = t / 12, rc = t % 12, r = rc / 4, c = rc % 4;
        const float* K = Ks + v * 9;
        const float* P = poses + v * 12;
        float s = K[r*3+0]*P[0*4+c] + K[r*3+1]*P[1*4+c] + K[r*3+2]*P[2*4+c];
        mats[v*12 + r*4 + c] = s;
    }
}

// ---- K1: G[v][y][x][j] = b1[j] + sum_c feats[v][c][y][x] * W1[c][j]  (NHWC) ----
__global__ void __launch_bounds__(256) k_g(const float* __restrict__ feats,
                                           const float* __restrict__ W1,
                                           const float* __restrict__ b1,
                                           float* __restrict__ G) {
    int t = blockIdx.x * 256 + threadIdx.x;    // NVIEW*HF*WF = 131072 threads
    int x = t % WF;
    int y = (t / WF) % HF;
    int v = t / (WF * HF);
    const float* fp = feats + ((size_t)(v * CIN) * HF + y) * WF + x;
    float f[CIN];
#pragma unroll
    for (int c = 0; c < CIN; c++) f[c] = fp[(size_t)c * HF * WF];
    float g[C1];
#pragma unroll
    for (int jj = 0; jj < C1; jj++) g[jj] = b1[jj];
#pragma unroll
    for (int c = 0; c < CIN; c++) {
        float fc = f[c];
#pragma unroll
        for (int jj = 0; jj < C1; jj++) g[jj] = fmaf(fc, W1[c*C1 + jj], g[jj]);
    }
    float4* outp = (float4*)(G + (size_t)t * C1);
#pragma unroll
    for (int q = 0; q < C1/4; q++)
        outp[q] = make_float4(g[4*q], g[4*q+1], g[4*q+2], g[4*q+3]);
}

// ---- K2: msum[v][j][k] = sum_i mask(v, i, j, k) ----
__global__ void __launch_bounds__(256) k_msum(const float* __restrict__ mats,
                                              const float* __restrict__ bbox,
                                              const int* __restrict__ ihp,
                                              const int* __restrict__ iwp,
                                              float* __restrict__ msum) {
    int t = blockIdx.x * 256 + threadIdx.x;    // NVIEW*64*64 = 32768
    int k = t & 63;
    int j = (t >> 6) & 63;
    int v = t >> 12;
    float img_w = (float)iwp[0], img_h = (float)ihp[0];
    float y = vox_coord(j, bbox[1]);
    float z = vox_coord(k, bbox[2]);
    const float* M = mats + v * 12;
    float s = 0.0f;
    for (int i = 0; i < RESO; i++) {
        float x = vox_coord(i, bbox[0]);
        float ix, iy, zc;
        proj_ixiy(M, x, y, z, img_w, img_h, ix, iy, zc);
        bool inb = (ix >= 0.0f) && (ix <= (float)(WF-1)) &&
                   (iy >= 0.0f) && (iy <= (float)(HF-1)) && (zc > 0.0f);
        s += inb ? 1.0f : 0.0f;
    }
    msum[t] = s;
}

// ---- K3: main — per voxel: loop views, blend G, MLP layers 2/3, moments ----
__global__ void __launch_bounds__(256) k_main(
    const float* __restrict__ G, const float* __restrict__ msum,
    const float* __restrict__ mats, const float* __restrict__ bbox,
    const int* __restrict__ ihp, const int* __restrict__ iwp,
    const float* __restrict__ W2, const float* __restrict__ b2,
    const float* __restrict__ W3, const float* __restrict__ b3,
    float* __restrict__ out) {
    int t = blockIdx.x * 256 + threadIdx.x;    // 262144 threads; i fastest (coalesced out)
    int i = t & 63;
    int j = (t >> 6) & 63;
    int k = t >> 12;
    float img_w = (float)iwp[0], img_h = (float)ihp[0];
    float x = vox_coord(i, bbox[0]);
    float y = vox_coord(j, bbox[1]);
    float z = vox_coord(k, bbox[2]);

    float M1[C3], Msq[C3];
    float S = 0.0f;
#pragma unroll
    for (int c = 0; c < C3; c++) { M1[c] = 0.0f; Msq[c] = 0.0f; }

#pragma unroll 1
    for (int v = 0; v < NVIEW; v++) {
        const float* M = mats + v * 12;
        float ix, iy, zc;
        proj_ixiy(M, x, y, z, img_w, img_h, ix, iy, zc);

        float fx0 = floorf(ix), fy0 = floorf(iy);
        float fx1 = fx0 + 1.0f, fy1 = fy0 + 1.0f;
        bool inb = (ix >= 0.0f) && (ix <= (float)(WF-1)) &&
                   (iy >= 0.0f) && (iy <= (float)(HF-1)) && (zc > 0.0f);
        float mvalid = inb ? 1.0f : 0.0f;
        int cx0 = (int)fminf(fmaxf(fx0, 0.0f), (float)(WF-1));
        int cx1 = (int)fminf(fmaxf(fx1, 0.0f), (float)(WF-1));
        int cy0 = (int)fminf(fmaxf(fy0, 0.0f), (float)(HF-1));
        int cy1 = (int)fminf(fmaxf(fy1, 0.0f), (float)(HF-1));
        float wnw = (fx1 - ix) * (fy1 - iy);
        float wne = (ix - fx0) * (fy1 - iy);
        float wsw = (fx1 - ix) * (iy - fy0);
        float wse = (ix - fx0) * (iy - fy0);

        const float4* Gv  = (const float4*)(G + (size_t)v * HF * WF * C1);
        const float4* pnw = Gv + (size_t)(cy0 * WF + cx0) * (C1/4);
        const float4* pne = Gv + (size_t)(cy0 * WF + cx1) * (C1/4);
        const float4* psw = Gv + (size_t)(cy1 * WF + cx0) * (C1/4);
        const float4* pse = Gv + (size_t)(cy1 * WF + cx1) * (C1/4);

        float h1[C1];
#pragma unroll
        for (int q = 0; q < C1/4; q++) {
            float4 a = pnw[q], b = pne[q], c4 = psw[q], d = pse[q];
            h1[4*q+0] = fmaxf(fmaf(wnw, a.x, fmaf(wne, b.x, fmaf(wsw, c4.x, wse * d.x))), 0.0f);
            h1[4*q+1] = fmaxf(fmaf(wnw, a.y, fmaf(wne, b.y, fmaf(wsw, c4.y, wse * d.y))), 0.0f);
            h1[4*q+2] = fmaxf(fmaf(wnw, a.z, fmaf(wne, b.z, fmaf(wsw, c4.z, wse * d.z))), 0.0f);
            h1[4*q+3] = fmaxf(fmaf(wnw, a.w, fmaf(wne, b.w, fmaf(wsw, c4.w, wse * d.w))), 0.0f);
        }

        float h2[C2];
#pragma unroll
        for (int o = 0; o < C2; o++) h2[o] = b2[o];
#pragma unroll
        for (int jj = 0; jj < C1; jj++) {
            float hv = h1[jj];
#pragma unroll
            for (int o = 0; o < C2; o++) h2[o] = fmaf(hv, W2[jj*C2 + o], h2[o]);
        }
#pragma unroll
        for (int o = 0; o < C2; o++) h2[o] = fmaxf(h2[o], 0.0f);

        float cp[C3];
#pragma unroll
        for (int c = 0; c < C3; c++) cp[c] = b3[c];
#pragma unroll
        for (int o = 0; o < C2; o++) {
            float hv = h2[o];
#pragma unroll
            for (int c = 0; c < C3; c++) cp[c] = fmaf(hv, W3[o*C3 + c], cp[c]);
        }

        float ms = msum[(v << 12) | (j << 6) | k];
        float w = mvalid / (ms + 1e-8f);
        S += w;
#pragma unroll
        for (int c = 0; c < C3; c++) {
            M1[c]  = fmaf(w, cp[c], M1[c]);
            Msq[c] = fmaf(w * cp[c], cp[c], Msq[c]);
        }
    }

    // out[0][ch][k][j][i]: ch 0..7 = mean, 8..15 = var = M2 + mean^2*(S-2)
    size_t ob = (size_t)k * 4096 + (size_t)j * 64 + (size_t)i;
#pragma unroll
    for (int c = 0; c < C3; c++) {
        out[(size_t)c * 262144 + ob] = M1[c];
        out[(size_t)(c + 8) * 262144 + ob] = fmaf(M1[c] * M1[c], S - 2.0f, Msq[c]);
    }
}

// ---- launch ----
extern "C" void kernel_launch(void* const* d_in, const int* in_sizes, int n_in,
                              void* d_out, int out_size, void* d_ws, size_t ws_size,
                              hipStream_t stream) {
    const float* feats = (const float*)d_in[0];
    const float* poses = (const float*)d_in[1];
    const float* Ks    = (const float*)d_in[2];
    const float* bbox  = (const float*)d_in[3];
    const int*   img_h = (const int*)d_in[4];
    const int*   img_w = (const int*)d_in[5];
    const float* W1    = (const float*)d_in[6];
    const float* b1    = (const float*)d_in[7];
    const float* W2    = (const float*)d_in[8];
    const float* b2    = (const float*)d_in[9];
    const float* W3    = (const float*)d_in[10];
    const float* b3    = (const float*)d_in[11];
    float* out = (float*)d_out;
    float* ws  = (float*)d_ws;

    float* mats = ws;           // 96 floats
    float* msum = ws + 128;     // 32768 floats
    float* G    = ws + 33024;   // NVIEW*HF*WF*C1 = 4,194,304 floats (16 MB), 16B-aligned

    hipLaunchKernelGGL(k_mats, dim3(1),    dim3(128), 0, stream, Ks, poses, mats);
    hipLaunchKernelGGL(k_g,    dim3(512),  dim3(256), 0, stream, feats, W1, b1, G);
    hipLaunchKernelGGL(k_msum, dim3(128),  dim3(256), 0, stream, mats, bbox, img_h, img_w, msum);
    hipLaunchKernelGGL(k_main, dim3(1024), dim3(256), 0, stream,
                       G, msum, mats, bbox, img_h, img_w, W2, b2, W3, b3, out);
}